// Round 5
// baseline (593.589 us; speedup 1.0000x reference)
//
#include <hip/hip_runtime.h>
#include <math.h>

#define N_NODE 100000
#define DEPTH  10
#define N_EDGE 1600000
#define D_FEAT 32
#define D_OUT  ((DEPTH + 1) * D_FEAT)   // 352 floats per node in output
#define NB_SCAN ((N_NODE + 255) / 256)  // 391 scan blocks

// clang-native vector types (accepted by __builtin_nontemporal_*)
typedef float        f32x4 __attribute__((ext_vector_type(4)));
typedef unsigned int u32x4 __attribute__((ext_vector_type(4)));
typedef int          i32x2 __attribute__((ext_vector_type(2)));

// ---------------------------------------------------------------------------
// bf16 helpers (bit-level, RTN-even)
// ---------------------------------------------------------------------------
__device__ inline unsigned short f32_to_bf16(float f) {
    unsigned int b = __float_as_uint(f);
    unsigned int r = (b + 0x7FFFu + ((b >> 16) & 1u)) >> 16;
    return (unsigned short)r;
}
__device__ inline unsigned int pack_bf16x2(float lo, float hi) {
    return (unsigned int)f32_to_bf16(lo) | ((unsigned int)f32_to_bf16(hi) << 16);
}

// ---------------------------------------------------------------------------
// Phase 1: degree count (in-degree over `row`)
// ---------------------------------------------------------------------------
__global__ void count_kernel(const int* __restrict__ row, int* __restrict__ cnt, int E) {
    int e = blockIdx.x * blockDim.x + threadIdx.x;
    if (e < E) atomicAdd(&cnt[row[e]], 1);
}

// ---------------------------------------------------------------------------
// Phase 2: hierarchical exclusive scan (3 kernels)
// ---------------------------------------------------------------------------
__device__ inline int wave_incl_scan(int v) {
    int lane = threadIdx.x & 63;
    #pragma unroll
    for (int off = 1; off < 64; off <<= 1) {
        int t = __shfl_up(v, off, 64);
        if (lane >= off) v += t;
    }
    return v;
}

__global__ void blockscan_kernel(const int* __restrict__ cnt, int* __restrict__ rowStart,
                                 int* __restrict__ blockSums, int n) {
    __shared__ int partials[4];
    int i = blockIdx.x * 256 + threadIdx.x;
    int v = (i < n) ? cnt[i] : 0;
    int incl = wave_incl_scan(v);
    int wid = threadIdx.x >> 6, lane = threadIdx.x & 63;
    if (lane == 63) partials[wid] = incl;
    __syncthreads();
    int woff = 0;
    #pragma unroll
    for (int w = 0; w < 4; ++w) woff += (w < wid) ? partials[w] : 0;
    if (i < n) rowStart[i] = woff + incl - v;               // block-local exclusive
    if (threadIdx.x == 255) blockSums[blockIdx.x] = woff + incl;
}

__global__ void scansums_kernel(int* __restrict__ blockSums, int nb) {
    __shared__ int partials[8];
    int i = threadIdx.x;                                    // 512 threads
    int v = (i < nb) ? blockSums[i] : 0;
    int incl = wave_incl_scan(v);
    int wid = i >> 6, lane = i & 63;
    if (lane == 63) partials[wid] = incl;
    __syncthreads();
    int woff = 0;
    #pragma unroll
    for (int w = 0; w < 8; ++w) woff += (w < wid) ? partials[w] : 0;
    if (i < nb) blockSums[i] = woff + incl - v;             // exclusive
    if (i == 511) blockSums[nb] = woff + incl;              // grand total
}

__global__ void addoffs_kernel(int* __restrict__ rowStart, const int* __restrict__ blockSums,
                               int n, int nb) {
    int i = blockIdx.x * 256 + threadIdx.x;
    if (i < n)  rowStart[i] += blockSums[i >> 8];
    if (i == n) rowStart[n] = blockSums[nb];
}

// ---------------------------------------------------------------------------
// Phase 3: dinv = (deg<0.5 ? deg+1 : deg)^-0.5
// ---------------------------------------------------------------------------
__global__ void dinv_kernel(const int* __restrict__ cnt, float* __restrict__ dinv, int n) {
    int i = blockIdx.x * blockDim.x + threadIdx.x;
    if (i < n) {
        float d = (float)cnt[i];
        if (d < 0.5f) d += 1.0f;
        dinv[i] = 1.0f / sqrtf(d);
    }
}

// ---------------------------------------------------------------------------
// Phase 4: scatter edges to CSR as combined 8B {col, val} entries.
// Nontemporal store: no L2 allocation -> partial lines merge downstream.
// ---------------------------------------------------------------------------
__global__ void scatter_kernel(const int* __restrict__ row, const int* __restrict__ col,
                               const float* __restrict__ eattr,
                               const int* __restrict__ rowStart, int* __restrict__ cnt,
                               const float* __restrict__ dinv,
                               i32x2* __restrict__ csr, int E) {
    int e = blockIdx.x * blockDim.x + threadIdx.x;
    if (e < E) {
        int r = row[e], c = col[e];
        int p = rowStart[r] + atomicSub(&cnt[r], 1) - 1;
        float val = dinv[r] * eattr[e] * dinv[c];
        i32x2 ent; ent.x = c; ent.y = __float_as_int(val);
        __builtin_nontemporal_store(ent, &csr[p]);
    }
}

// ---------------------------------------------------------------------------
// alphas_t[L] = tanh(alphas[L]) (BASE_ALPHA = 1)
// ---------------------------------------------------------------------------
__global__ void alpha_kernel(const float* __restrict__ alphas, float* __restrict__ alphaT) {
    int i = threadIdx.x;
    if (i <= DEPTH) alphaT[i] = tanhf(alphas[i]);
}

// ---------------------------------------------------------------------------
// x_0: out[node,0,:] = x (fp32, nt) and h0[node,:] = bf16(x)
// ---------------------------------------------------------------------------
__global__ void copyx_kernel(const f32x4* __restrict__ x4, f32x4* __restrict__ out4,
                             unsigned int* __restrict__ h0) {
    int i = blockIdx.x * blockDim.x + threadIdx.x;
    if (i < N_NODE * 8) {
        int node = i >> 3, q = i & 7;
        f32x4 v = x4[i];
        __builtin_nontemporal_store(v, &out4[(size_t)node * 88 + q]);
        h0[i * 2]     = pack_bf16x2(v.x, v.y);
        h0[i * 2 + 1] = pack_bf16x2(v.z, v.w);
    }
}

// ---------------------------------------------------------------------------
// Phase 5 (x10): SpMM level L. ONE WAVE PER ROW, 16 edge slots x 4 feat-octs.
// lane = (s,q): s = lane>>2 (edge slot 0..15), q = lane&3 (8 feats, 16B).
// Typical row (deg~16) = ONE iteration: 128B csr read + 16-line gather.
// csr/out are nontemporal (L2 reserved for h). Reduce across slots via xor.
// ---------------------------------------------------------------------------
__global__ __launch_bounds__(256) void spmm_kernel(const int* __restrict__ rowStart,
                                                   const i32x2* __restrict__ csr,
                                                   const float* __restrict__ alphaT,
                                                   int L,
                                                   const u32x4* __restrict__ h_prev,
                                                   u32x4* __restrict__ h_cur,
                                                   f32x4* __restrict__ out4) {
    int rowid = (int)((blockIdx.x * 256 + threadIdx.x) >> 6);
    if (rowid >= N_NODE) return;
    int lane = threadIdx.x & 63;
    int s = lane >> 2;                 // edge slot (16)
    int q = lane & 3;                  // feat oct (4 x 8 feats)

    int start = rowStart[rowid];
    int end   = rowStart[rowid + 1];

    float acc[8] = {0.f, 0.f, 0.f, 0.f, 0.f, 0.f, 0.f, 0.f};
    for (int e = start + s; e < end; e += 16) {
        i32x2 cv = __builtin_nontemporal_load(&csr[e]);
        float v  = __int_as_float(cv.y);
        u32x4 h  = h_prev[(size_t)cv.x * 4 + q];
        acc[0] += v * __uint_as_float(h.x << 16);
        acc[1] += v * __uint_as_float(h.x & 0xFFFF0000u);
        acc[2] += v * __uint_as_float(h.y << 16);
        acc[3] += v * __uint_as_float(h.y & 0xFFFF0000u);
        acc[4] += v * __uint_as_float(h.z << 16);
        acc[5] += v * __uint_as_float(h.z & 0xFFFF0000u);
        acc[6] += v * __uint_as_float(h.w << 16);
        acc[7] += v * __uint_as_float(h.w & 0xFFFF0000u);
    }

    // reduce across the 16 edge slots (lane-xor 4,8,16,32)
    #pragma unroll
    for (int m = 4; m < 64; m <<= 1) {
        #pragma unroll
        for (int k = 0; k < 8; ++k) acc[k] += __shfl_xor(acc[k], m, 64);
    }

    if (s == 0) {   // lanes 0..3 hold feats q*8..q*8+7
        float a = alphaT[L];
        #pragma unroll
        for (int k = 0; k < 8; ++k) acc[k] *= a;
        size_t ob = (size_t)rowid * 88 + L * 8 + q * 2;
        f32x4 o0; o0.x = acc[0]; o0.y = acc[1]; o0.z = acc[2]; o0.w = acc[3];
        f32x4 o1; o1.x = acc[4]; o1.y = acc[5]; o1.z = acc[6]; o1.w = acc[7];
        __builtin_nontemporal_store(o0, &out4[ob]);
        __builtin_nontemporal_store(o1, &out4[ob + 1]);
        if (L < DEPTH) {
            u32x4 hh;
            hh.x = pack_bf16x2(acc[0], acc[1]);
            hh.y = pack_bf16x2(acc[2], acc[3]);
            hh.z = pack_bf16x2(acc[4], acc[5]);
            hh.w = pack_bf16x2(acc[6], acc[7]);
            __builtin_nontemporal_store(hh, &h_cur[(size_t)rowid * 4 + q]);
        }
    }
}

// ---------------------------------------------------------------------------
extern "C" void kernel_launch(void* const* d_in, const int* in_sizes, int n_in,
                              void* d_out, int out_size, void* d_ws, size_t ws_size,
                              hipStream_t stream) {
    const float* x      = (const float*)d_in[0];
    const int*   eidx   = (const int*)d_in[1];     // (2, E): row = [0,E), col = [E,2E)
    const float* eattr  = (const float*)d_in[2];
    const float* alphas = (const float*)d_in[3];
    float* out = (float*)d_out;

    const int* row = eidx;
    const int* col = eidx + N_EDGE;

    // ---- workspace partition (256B aligned) ----
    char* p = (char*)d_ws;
    auto alloc = [&](size_t bytes) { char* r = p; p += (bytes + 255) & ~(size_t)255; return (void*)r; };
    int*   cnt       = (int*)  alloc((size_t)N_NODE * 4);
    int*   rowStart  = (int*)  alloc((size_t)(N_NODE + 1) * 4);
    int*   blockSums = (int*)  alloc((size_t)(NB_SCAN + 1) * 4);
    float* dinv      = (float*)alloc((size_t)N_NODE * 4);
    float* alphaT    = (float*)alloc(64);
    u32x4* h0        = (u32x4*)alloc((size_t)N_NODE * 64);  // bf16 [N][32]
    u32x4* h1        = (u32x4*)alloc((size_t)N_NODE * 64);
    i32x2* csr       = (i32x2*)alloc((size_t)N_EDGE * 8);
    (void)ws_size; (void)in_sizes; (void)n_in; (void)out_size;

    (void)hipMemsetAsync(cnt, 0, (size_t)N_NODE * 4, stream);

    const int TB = 256;
    int eBlocks = (N_EDGE + TB - 1) / TB;
    int nBlocks = (N_NODE + TB - 1) / TB;

    count_kernel<<<eBlocks, TB, 0, stream>>>(row, cnt, N_EDGE);
    blockscan_kernel<<<NB_SCAN, TB, 0, stream>>>(cnt, rowStart, blockSums, N_NODE);
    scansums_kernel<<<1, 512, 0, stream>>>(blockSums, NB_SCAN);
    addoffs_kernel<<<(N_NODE + 1 + TB - 1) / TB, TB, 0, stream>>>(rowStart, blockSums, N_NODE, NB_SCAN);
    dinv_kernel<<<nBlocks, TB, 0, stream>>>(cnt, dinv, N_NODE);
    scatter_kernel<<<eBlocks, TB, 0, stream>>>(row, col, eattr, rowStart, cnt, dinv, csr, N_EDGE);
    alpha_kernel<<<1, 64, 0, stream>>>(alphas, alphaT);
    copyx_kernel<<<(N_NODE * 8 + TB - 1) / TB, TB, 0, stream>>>((const f32x4*)x, (f32x4*)out,
                                                                (unsigned int*)h0);

    int spmmBlocks = (N_NODE * 64 + TB - 1) / TB;  // one 64-lane wave per row
    for (int L = 1; L <= DEPTH; ++L) {
        const u32x4* hp = (L & 1) ? h0 : h1;
        u32x4*       hc = (L & 1) ? h1 : h0;
        spmm_kernel<<<spmmBlocks, TB, 0, stream>>>(rowStart, csr, alphaT, L, hp, hc,
                                                   (f32x4*)out);
    }
}